// Round 20
// baseline (391.029 us; speedup 1.0000x reference)
//
#include <hip/hip_runtime.h>
#include <hip/hip_bf16.h>

#define NN     200000
#define FEATD  64
#define BN     4096
#define DEG    32
#define PP     2048
#define EMB    64
#define EPSV   1e-8f
#define NT32   6250        // NN / 32 exactly
#define GRID   768         // 3 blocks/CU needed; 4/CU capacity -> co-resident

// ws layout (float offsets)
#define WS_SC    0          // float4[NN]
#define WS_CTR   800000     // 2 ints (barrier + finisher), memset each launch
#define WS_PL    810000     // loss partials [(r*4096+b)*2 + {0,1}]

#define CSTRIDE 264

typedef short  bf16x8 __attribute__((ext_vector_type(8)));
typedef float  f32x4  __attribute__((ext_vector_type(4)));

__device__ __forceinline__ unsigned int bfr(float x) {
    unsigned int u = __float_as_uint(x);
    return (u + 0x7FFFu + ((u >> 16) & 1u)) & 0xFFFF0000u;
}

// ---------------------------------------------------------------- fused
// Phase A: sim=relu(F@R) stats via MFMA hi/lo split (r16 32-node tiles).
// Grid barrier (all 768 blocks co-resident by construction).
// Phase CD: per-wave b: score/top-k/aggregate/rfeat -> LDS cat, then
// out[:,b] = relu(cat . weight). Loss partials to private slots; last
// finisher computes pe-norms + mean_pos + loss.
__global__ __launch_bounds__(256, 4) void fused_all(
    const int* __restrict__ nodes,
    const int* __restrict__ n1, const int* __restrict__ n2, const int* __restrict__ n3,
    const int* __restrict__ pos_nodes, const float* __restrict__ features,
    const float* __restrict__ weight, const float* __restrict__ rsim,
    const float* __restrict__ pos_embs,
    const float* __restrict__ W1, const float* __restrict__ W2, const float* __restrict__ W3,
    const int* __restrict__ smp, float4* __restrict__ node_sc,
    float* __restrict__ plossws, int* __restrict__ ctr, float* __restrict__ out)
{
    __shared__ union {
        unsigned int lds[4][2][8][32][4];       // A phase: 32KB
        struct {                                 // CD phase: ~7KB
            float  cat_b[4 * CSTRIDE];
            float  trans[4 * 65];
            int    sel_ids[4][32];
            float4 aggl[4][16];
            float  invpe_sm[3];
            float  wsum[4][3];
            float  lsum[3][2];
        } c;
    } sm;
    __shared__ float pel[192];
    __shared__ int wflag;

    int t = threadIdx.x, w = t >> 6, l = t & 63;
    int lg = l >> 4, lr = l & 15;
    const float4* Gf = (const float4*)features;
    int k = smp[0];

    if (t < 192) pel[t] = pos_embs[t];

    // ---- R fragments (hi/lo), once per wave
    bf16x8 rhi[2][4], rlo[2][4];
#pragma unroll
    for (int kk = 0; kk < 2; ++kk)
#pragma unroll
        for (int nf = 0; nf < 4; ++nf) {
            union { unsigned int u[4]; bf16x8 v; } H, L;
#pragma unroll
            for (int i = 0; i < 4; ++i) {
                int k0 = kk * 32 + lg * 8 + i * 2;
                int j  = nf * 16 + lr;
                float x0 = rsim[k0 * 64 + j];
                float x1 = rsim[(k0 + 1) * 64 + j];
                unsigned int r0 = bfr(x0), r1 = bfr(x1);
                H.u[i] = (r0 >> 16) | r1;
                float l0 = x0 - __uint_as_float(r0);
                float l1 = x1 - __uint_as_float(r1);
                L.u[i] = (__float_as_uint(l0) >> 16)
                       | (__float_as_uint(l1) & 0xFFFF0000u);
            }
            rhi[kk][nf] = H.v; rlo[kk][nf] = L.v;
        }
    __syncthreads();                             // pel ready

    // ================= Phase A =================
    unsigned int (*Lhi)[32][4] = sm.lds[w][0];
    unsigned int (*Llo)[32][4] = sm.lds[w][1];

    for (int tile = blockIdx.x * 4 + w; tile < NT32; tile += GRID * 4) {
        const float4* src = Gf + (size_t)tile * 512;
#pragma unroll
        for (int s = 0; s < 8; ++s) {
            float4 v = src[s * 64 + l];
            int node = s * 4 + lg;
            int kg = lr >> 1, half = lr & 1;
            unsigned int rx = bfr(v.x), ry = bfr(v.y);
            unsigned int rz = bfr(v.z), rw = bfr(v.w);
            unsigned int h0 = (rx >> 16) | ry;
            unsigned int h1 = (rz >> 16) | rw;
            float lx = v.x - __uint_as_float(rx), ly = v.y - __uint_as_float(ry);
            float lz = v.z - __uint_as_float(rz), lw = v.w - __uint_as_float(rw);
            unsigned int l0 = (__float_as_uint(lx) >> 16)
                            | (__float_as_uint(ly) & 0xFFFF0000u);
            unsigned int l1 = (__float_as_uint(lz) >> 16)
                            | (__float_as_uint(lw) & 0xFFFF0000u);
            uint2* dh = (uint2*)&Lhi[kg][node ^ kg][half * 2];
            uint2* dl = (uint2*)&Llo[kg][node ^ kg][half * 2];
            *dh = make_uint2(h0, h1);
            *dl = make_uint2(l0, l1);
        }
        const bf16x8* ph = (const bf16x8*)Lhi;
        const bf16x8* pl = (const bf16x8*)Llo;

#pragma unroll
        for (int mf = 0; mf < 2; ++mf) {
            int node = mf * 16 + lr;
            bf16x8 ah0 = ph[lg * 32 + (node ^ lg)];
            bf16x8 ah1 = ph[(4 + lg) * 32 + (node ^ (4 + lg))];
            bf16x8 al0 = pl[lg * 32 + (node ^ lg)];
            bf16x8 al1 = pl[(4 + lg) * 32 + (node ^ (4 + lg))];

            f32x4 acc[4];
#pragma unroll
            for (int nf = 0; nf < 4; ++nf) acc[nf] = (f32x4)(0.f);
#pragma unroll
            for (int nf = 0; nf < 4; ++nf) {
                acc[nf] = __builtin_amdgcn_mfma_f32_16x16x32_bf16(ah0, rhi[0][nf], acc[nf], 0, 0, 0);
                acc[nf] = __builtin_amdgcn_mfma_f32_16x16x32_bf16(ah1, rhi[1][nf], acc[nf], 0, 0, 0);
                acc[nf] = __builtin_amdgcn_mfma_f32_16x16x32_bf16(ah0, rlo[0][nf], acc[nf], 0, 0, 0);
                acc[nf] = __builtin_amdgcn_mfma_f32_16x16x32_bf16(ah1, rlo[1][nf], acc[nf], 0, 0, 0);
                acc[nf] = __builtin_amdgcn_mfma_f32_16x16x32_bf16(al0, rhi[0][nf], acc[nf], 0, 0, 0);
                acc[nf] = __builtin_amdgcn_mfma_f32_16x16x32_bf16(al1, rhi[1][nf], acc[nf], 0, 0, 0);
            }

            float q[4] = {0,0,0,0}, s0[4] = {0,0,0,0};
            float s1[4] = {0,0,0,0}, s2[4] = {0,0,0,0};
#pragma unroll
            for (int reg = 0; reg < 4; ++reg)
#pragma unroll
                for (int nf = 0; nf < 4; ++nf) {
                    float v = fmaxf(acc[nf][reg], 0.f);
                    int j = nf * 16 + lr;
                    q[reg]  += v * v;
                    s0[reg] += v * pel[j];
                    s1[reg] += v * pel[64 + j];
                    s2[reg] += v * pel[128 + j];
                }
#pragma unroll
            for (int o = 1; o < 16; o <<= 1)
#pragma unroll
                for (int reg = 0; reg < 4; ++reg) {
                    q[reg]  += __shfl_xor(q[reg],  o);
                    s0[reg] += __shfl_xor(s0[reg], o);
                    s1[reg] += __shfl_xor(s1[reg], o);
                    s2[reg] += __shfl_xor(s2[reg], o);
                }
            if (lr < 4) {
                int rr = l & 3;
                float o0 = (rr==0)?s0[0]:(rr==1)?s0[1]:(rr==2)?s0[2]:s0[3];
                float o1 = (rr==0)?s1[0]:(rr==1)?s1[1]:(rr==2)?s1[2]:s1[3];
                float o2 = (rr==0)?s2[0]:(rr==1)?s2[1]:(rr==2)?s2[2]:s2[3];
                float oq = (rr==0)?q[0] :(rr==1)?q[1] :(rr==2)?q[2] :q[3];
                node_sc[tile * 32 + mf * 16 + lg * 4 + rr] =
                    make_float4(o0, o1, o2, sqrtf(oq));
            }
        }
    }

    // ================= grid barrier =================
    __threadfence();
    __syncthreads();
    if (t == 0) {
        __hip_atomic_fetch_add(&ctr[0], 1, __ATOMIC_ACQ_REL, __HIP_MEMORY_SCOPE_AGENT);
        while (__hip_atomic_load(&ctr[0], __ATOMIC_ACQUIRE, __HIP_MEMORY_SCOPE_AGENT) < GRID)
            __builtin_amdgcn_s_sleep(2);
    }
    __syncthreads();
    (void)__hip_atomic_load(&ctr[0], __ATOMIC_ACQUIRE, __HIP_MEMORY_SCOPE_AGENT);

    // ================= Phase CD =================
    float ipe[3];
#pragma unroll
    for (int r = 0; r < 3; ++r) {
        float pv = pel[r * 64 + l];
        float qq = pv * pv;
#pragma unroll
        for (int o = 1; o < 64; o <<= 1) qq += __shfl_xor(qq, o);
        ipe[r] = 1.f / fmaxf(sqrtf(qq), EPSV);
    }

    const float4* F = (const float4*)features;
    for (int grp = blockIdx.x; grp < BN / 4; grp += GRID) {
        int b0 = grp * 4;
        int b = b0 + w;
        // center row (wave-local)
        sm.c.cat_b[w * CSTRIDE + l] = features[(size_t)nodes[b] * FEATD + l];

#pragma unroll
        for (int r = 0; r < 3; ++r) {
            const int*   neigh = (r == 0) ? n1 : (r == 1) ? n2 : n3;
            const float* W     = (r == 0) ? W1 : (r == 1) ? W2 : W3;

            float s = -1e30f;
            int   n = 0;
            if (l < 32) {
                n = neigh[b * DEG + l];
                float4 sc = node_sc[n];
                float num = (r == 0) ? sc.x : (r == 1) ? sc.y : sc.z;
                s = num * ipe[r] / fmaxf(sc.w, EPSV);
            }
            int cnt = 0;
#pragma unroll
            for (int d2 = 0; d2 < 32; ++d2) {
                float v = __shfl(s, d2);
                cnt += ((v > s) || (v == s && d2 < l)) ? 1 : 0;
            }
            bool sel = (l < 32) && (cnt < k);
            if (sel) sm.c.sel_ids[w][cnt] = n;

            float sp = sel ? s : 0.f;
            float sq = sel ? s * s : 0.f;
#pragma unroll
            for (int off = 32; off; off >>= 1) {
                sp += __shfl_down(sp, off);
                sq += __shfl_down(sq, off);
            }
            if (l == 0) {
                plossws[(r * 4096 + b) * 2]     = sp;
                plossws[(r * 4096 + b) * 2 + 1] = sq;
            }

            int col   = l & 15;
            int rbase = l >> 4;
            float4 a = make_float4(0.f, 0.f, 0.f, 0.f);
            if (k == 16) {
                int nid0 = sm.c.sel_ids[w][rbase];
                int nid1 = sm.c.sel_ids[w][rbase + 4];
                int nid2 = sm.c.sel_ids[w][rbase + 8];
                int nid3 = sm.c.sel_ids[w][rbase + 12];
                float4 v0 = F[(size_t)nid0 * 16 + col];
                float4 v1 = F[(size_t)nid1 * 16 + col];
                float4 v2 = F[(size_t)nid2 * 16 + col];
                float4 v3 = F[(size_t)nid3 * 16 + col];
                a.x = v0.x + v1.x + v2.x + v3.x;
                a.y = v0.y + v1.y + v2.y + v3.y;
                a.z = v0.z + v1.z + v2.z + v3.z;
                a.w = v0.w + v1.w + v2.w + v3.w;
            } else {
                for (int row0 = 0; row0 < k; row0 += 4) {
                    int row = row0 + rbase;
                    if (row < k) {
                        int nid = sm.c.sel_ids[w][row];
                        float4 v = F[(size_t)nid * 16 + col];
                        a.x += v.x; a.y += v.y; a.z += v.z; a.w += v.w;
                    }
                }
            }
#pragma unroll
            for (int off = 16; off <= 32; off <<= 1) {
                a.x += __shfl_xor(a.x, off);
                a.y += __shfl_xor(a.y, off);
                a.z += __shfl_xor(a.z, off);
                a.w += __shfl_xor(a.w, off);
            }
            float inv_k = 1.f / (float)k;
            a.x *= inv_k; a.y *= inv_k; a.z *= inv_k; a.w *= inv_k;
            if (l < 16) sm.c.aggl[w][l] = a;

            float acc = 0.f;
#pragma unroll
            for (int j4 = 0; j4 < 16; ++j4) {
                float4 ag = sm.c.aggl[w][j4];
                acc += ag.x * W[(j4 * 4 + 0) * EMB + l]
                     + ag.y * W[(j4 * 4 + 1) * EMB + l]
                     + ag.z * W[(j4 * 4 + 2) * EMB + l]
                     + ag.w * W[(j4 * 4 + 3) * EMB + l];
            }
            sm.c.cat_b[w * CSTRIDE + 64 + r * 64 + l] = fmaxf(acc, 0.f);
        }

        // ---- D: out[:, b] (wave-local cat row)
        float acc0 = 0.f;
        const float* cp = &sm.c.cat_b[w * CSTRIDE];
        for (int i0 = 0; i0 < 256; i0 += 16) {
            float wq[16];
#pragma unroll
            for (int u = 0; u < 16; ++u)
                wq[u] = weight[(i0 + u) * EMB + l];
#pragma unroll
            for (int u = 0; u < 16; ++u)
                acc0 += wq[u] * cp[i0 + u];
        }
        sm.c.trans[w * 65 + l] = fmaxf(acc0, 0.f);
        __syncthreads();
        { int e = t >> 2, bb = t & 3;
          out[(size_t)e * BN + b0 + bb] = sm.c.trans[bb * 65 + e]; }
        __syncthreads();
    }

    // ================= last-finisher loss tail =================
    __threadfence();
    if (t == 0) {
        int old = __hip_atomic_fetch_add(&ctr[1], 1, __ATOMIC_ACQ_REL, __HIP_MEMORY_SCOPE_AGENT);
        wflag = (old == GRID - 1);
    }
    __syncthreads();
    if (!wflag) return;
    (void)__hip_atomic_load(&ctr[1], __ATOMIC_ACQUIRE, __HIP_MEMORY_SCOPE_AGENT);

    float pv = (t < 192) ? pel[t] : 0.f;
    float q = pv * pv;
#pragma unroll
    for (int o = 1; o < 64; o <<= 1) q += __shfl_xor(q, o);
    if (t < 192 && l == 0)
        sm.c.invpe_sm[w] = 1.f / fmaxf(sqrtf(q), EPSV);
    __syncthreads();

    float m0 = 0.f, m1 = 0.f, m2 = 0.f;
    for (int p = t; p < PP; p += 256) {
        int n = pos_nodes[p];
        float4 sc = node_sc[n];
        float invn = 1.f / fmaxf(sc.w, EPSV);
        m0 += sc.x * sm.c.invpe_sm[0] * invn;
        m1 += sc.y * sm.c.invpe_sm[1] * invn;
        m2 += sc.z * sm.c.invpe_sm[2] * invn;
    }
#pragma unroll
    for (int o = 1; o < 64; o <<= 1) {
        m0 += __shfl_xor(m0, o);
        m1 += __shfl_xor(m1, o);
        m2 += __shfl_xor(m2, o);
    }
    if (l == 0) { sm.c.wsum[w][0] = m0; sm.c.wsum[w][1] = m1; sm.c.wsum[w][2] = m2; }

    if (w < 3) {
        float s1 = 0.f, s2 = 0.f;
        const float2* pl2 = (const float2*)plossws;
        for (int i = l; i < 4096; i += 64) {
            float2 v = pl2[w * 4096 + i];
            s1 += v.x; s2 += v.y;
        }
#pragma unroll
        for (int o = 1; o < 64; o <<= 1) {
            s1 += __shfl_xor(s1, o);
            s2 += __shfl_xor(s2, o);
        }
        if (l == 0) { sm.c.lsum[w][0] = s1; sm.c.lsum[w][1] = s2; }
    }
    __syncthreads();

    if (t == 0) {
        float N = (float)BN * (float)k;
        float loss = 0.f;
#pragma unroll
        for (int r = 0; r < 3; ++r) {
            float mp = (sm.c.wsum[0][r] + sm.c.wsum[1][r] +
                        sm.c.wsum[2][r] + sm.c.wsum[3][r]) / (float)PP;
            float s1 = sm.c.lsum[r][0], s2 = sm.c.lsum[r][1];
            loss += s2 / N - 2.f * mp * s1 / N + mp * mp;
        }
        out[(size_t)EMB * BN] = loss / 3.f;
    }
}

// ----------------------------------------------------------------
extern "C" void kernel_launch(void* const* d_in, const int* in_sizes, int n_in,
                              void* d_out, int out_size, void* d_ws, size_t ws_size,
                              hipStream_t stream) {
    const int*   nodes     = (const int*)  d_in[0];
    // d_in[1] labels: unused
    const int*   neigh1    = (const int*)  d_in[2];
    const int*   neigh2    = (const int*)  d_in[3];
    const int*   neigh3    = (const int*)  d_in[4];
    const int*   pos_nodes = (const int*)  d_in[5];
    const float* features  = (const float*)d_in[6];
    const float* weight    = (const float*)d_in[7];
    const float* rsim      = (const float*)d_in[8];
    const float* pos_embs  = (const float*)d_in[9];
    const float* W1        = (const float*)d_in[10];
    const float* W2        = (const float*)d_in[11];
    const float* W3        = (const float*)d_in[12];
    const int*   smp       = (const int*)  d_in[13];
    float* out = (float*)d_out;
    float* ws  = (float*)d_ws;

    float4* node_sc = (float4*)(ws + WS_SC);
    int*    ctr     = (int*)(ws + WS_CTR);
    float*  plossws = ws + WS_PL;

    hipMemsetAsync((void*)ctr, 0, 8, stream);    // barrier + finisher counters
    fused_all<<<dim3(GRID), dim3(256), 0, stream>>>(
        nodes, neigh1, neigh2, neigh3, pos_nodes, features, weight,
        rsim, pos_embs, W1, W2, W3, smp, node_sc, plossws, ctr, out);
}

// Round 21
// 373.085 us; speedup vs baseline: 1.0481x; 1.0481x over previous
//
#include <hip/hip_runtime.h>
#include <hip/hip_bf16.h>

#define NN     200000
#define FEATD  64
#define BN     4096
#define DEG    32
#define PP     2048
#define EMB    64
#define EPSV   1e-8f
#define NT32   6250        // NN / 32 exactly
#define GRID   768         // exactly 3 blocks/CU; capacity 4/CU (40KB LDS)

// ws layout (float offsets)
#define WS_SC    0          // float4[NN]
#define WS_CTR   800000     // 2 ints (barrier + finisher), memset each launch
#define WS_PL    810000     // loss partials [(r*4096+b)*2 + {0,1}]

#define CSTRIDE 264

typedef short  bf16x8 __attribute__((ext_vector_type(8)));
typedef float  f32x4  __attribute__((ext_vector_type(4)));

__device__ __forceinline__ unsigned int bfr(float x) {
    unsigned int u = __float_as_uint(x);
    return (u + 0x7FFFu + ((u >> 16) & 1u)) & 0xFFFF0000u;
}

// ---------------------------------------------------------------- fused
// r20 retry with the spill fixed: launch_bounds(256,3) (VGPR cap ~170),
// NO union (A-LDS and CD-LDS separate, 40KB), R fragments scoped to
// phase A only. Grid barrier between phases (768 co-resident blocks).
__global__ __launch_bounds__(256, 3) void fused_all(
    const int* __restrict__ nodes,
    const int* __restrict__ n1, const int* __restrict__ n2, const int* __restrict__ n3,
    const int* __restrict__ pos_nodes, const float* __restrict__ features,
    const float* __restrict__ weight, const float* __restrict__ rsim,
    const float* __restrict__ pos_embs,
    const float* __restrict__ W1, const float* __restrict__ W2, const float* __restrict__ W3,
    const int* __restrict__ smp, float4* __restrict__ node_sc,
    float* __restrict__ plossws, int* __restrict__ ctr, float* __restrict__ out)
{
    __shared__ unsigned int alds[4][2][8][32][4];   // A phase, 32KB
    __shared__ float  cat_b[4 * CSTRIDE];
    __shared__ float  trans[4 * 65];
    __shared__ int    sel_ids[4][32];
    __shared__ float4 aggl[4][16];
    __shared__ float  invpe_sm[3];
    __shared__ float  wsum[4][3];
    __shared__ float  lsum[3][2];
    __shared__ float  pel[192];
    __shared__ int    wflag;

    int t = threadIdx.x, w = t >> 6, l = t & 63;
    int lg = l >> 4, lr = l & 15;
    const float4* Gf = (const float4*)features;
    int k = smp[0];

    if (t < 192) pel[t] = pos_embs[t];
    __syncthreads();

    // ================= Phase A (R fragments scoped here) =================
    {
        bf16x8 rhi[2][4], rlo[2][4];
#pragma unroll
        for (int kk = 0; kk < 2; ++kk)
#pragma unroll
            for (int nf = 0; nf < 4; ++nf) {
                union { unsigned int u[4]; bf16x8 v; } H, L;
#pragma unroll
                for (int i = 0; i < 4; ++i) {
                    int k0 = kk * 32 + lg * 8 + i * 2;
                    int j  = nf * 16 + lr;
                    float x0 = rsim[k0 * 64 + j];
                    float x1 = rsim[(k0 + 1) * 64 + j];
                    unsigned int r0 = bfr(x0), r1 = bfr(x1);
                    H.u[i] = (r0 >> 16) | r1;
                    float l0 = x0 - __uint_as_float(r0);
                    float l1 = x1 - __uint_as_float(r1);
                    L.u[i] = (__float_as_uint(l0) >> 16)
                           | (__float_as_uint(l1) & 0xFFFF0000u);
                }
                rhi[kk][nf] = H.v; rlo[kk][nf] = L.v;
            }

        unsigned int (*Lhi)[32][4] = alds[w][0];
        unsigned int (*Llo)[32][4] = alds[w][1];

        for (int tile = blockIdx.x * 4 + w; tile < NT32; tile += GRID * 4) {
            const float4* src = Gf + (size_t)tile * 512;
#pragma unroll
            for (int s = 0; s < 8; ++s) {
                float4 v = src[s * 64 + l];
                int node = s * 4 + lg;
                int kg = lr >> 1, half = lr & 1;
                unsigned int rx = bfr(v.x), ry = bfr(v.y);
                unsigned int rz = bfr(v.z), rw = bfr(v.w);
                unsigned int h0 = (rx >> 16) | ry;
                unsigned int h1 = (rz >> 16) | rw;
                float lx = v.x - __uint_as_float(rx), ly = v.y - __uint_as_float(ry);
                float lz = v.z - __uint_as_float(rz), lw = v.w - __uint_as_float(rw);
                unsigned int l0 = (__float_as_uint(lx) >> 16)
                                | (__float_as_uint(ly) & 0xFFFF0000u);
                unsigned int l1 = (__float_as_uint(lz) >> 16)
                                | (__float_as_uint(lw) & 0xFFFF0000u);
                uint2* dh = (uint2*)&Lhi[kg][node ^ kg][half * 2];
                uint2* dl = (uint2*)&Llo[kg][node ^ kg][half * 2];
                *dh = make_uint2(h0, h1);
                *dl = make_uint2(l0, l1);
            }
            const bf16x8* ph = (const bf16x8*)Lhi;
            const bf16x8* pl = (const bf16x8*)Llo;

#pragma unroll
            for (int mf = 0; mf < 2; ++mf) {
                int node = mf * 16 + lr;
                bf16x8 ah0 = ph[lg * 32 + (node ^ lg)];
                bf16x8 ah1 = ph[(4 + lg) * 32 + (node ^ (4 + lg))];
                bf16x8 al0 = pl[lg * 32 + (node ^ lg)];
                bf16x8 al1 = pl[(4 + lg) * 32 + (node ^ (4 + lg))];

                f32x4 acc[4];
#pragma unroll
                for (int nf = 0; nf < 4; ++nf) acc[nf] = (f32x4)(0.f);
#pragma unroll
                for (int nf = 0; nf < 4; ++nf) {
                    acc[nf] = __builtin_amdgcn_mfma_f32_16x16x32_bf16(ah0, rhi[0][nf], acc[nf], 0, 0, 0);
                    acc[nf] = __builtin_amdgcn_mfma_f32_16x16x32_bf16(ah1, rhi[1][nf], acc[nf], 0, 0, 0);
                    acc[nf] = __builtin_amdgcn_mfma_f32_16x16x32_bf16(ah0, rlo[0][nf], acc[nf], 0, 0, 0);
                    acc[nf] = __builtin_amdgcn_mfma_f32_16x16x32_bf16(ah1, rlo[1][nf], acc[nf], 0, 0, 0);
                    acc[nf] = __builtin_amdgcn_mfma_f32_16x16x32_bf16(al0, rhi[0][nf], acc[nf], 0, 0, 0);
                    acc[nf] = __builtin_amdgcn_mfma_f32_16x16x32_bf16(al1, rhi[1][nf], acc[nf], 0, 0, 0);
                }

                float q[4] = {0,0,0,0}, s0[4] = {0,0,0,0};
                float s1[4] = {0,0,0,0}, s2[4] = {0,0,0,0};
#pragma unroll
                for (int reg = 0; reg < 4; ++reg)
#pragma unroll
                    for (int nf = 0; nf < 4; ++nf) {
                        float v = fmaxf(acc[nf][reg], 0.f);
                        int j = nf * 16 + lr;
                        q[reg]  += v * v;
                        s0[reg] += v * pel[j];
                        s1[reg] += v * pel[64 + j];
                        s2[reg] += v * pel[128 + j];
                    }
#pragma unroll
                for (int o = 1; o < 16; o <<= 1)
#pragma unroll
                    for (int reg = 0; reg < 4; ++reg) {
                        q[reg]  += __shfl_xor(q[reg],  o);
                        s0[reg] += __shfl_xor(s0[reg], o);
                        s1[reg] += __shfl_xor(s1[reg], o);
                        s2[reg] += __shfl_xor(s2[reg], o);
                    }
                if (lr < 4) {
                    int rr = l & 3;
                    float o0 = (rr==0)?s0[0]:(rr==1)?s0[1]:(rr==2)?s0[2]:s0[3];
                    float o1 = (rr==0)?s1[0]:(rr==1)?s1[1]:(rr==2)?s1[2]:s1[3];
                    float o2 = (rr==0)?s2[0]:(rr==1)?s2[1]:(rr==2)?s2[2]:s2[3];
                    float oq = (rr==0)?q[0] :(rr==1)?q[1] :(rr==2)?q[2] :q[3];
                    node_sc[tile * 32 + mf * 16 + lg * 4 + rr] =
                        make_float4(o0, o1, o2, sqrtf(oq));
                }
            }
        }
    }   // R fragments dead here

    // ================= grid barrier =================
    __threadfence();
    __syncthreads();
    if (t == 0) {
        __hip_atomic_fetch_add(&ctr[0], 1, __ATOMIC_ACQ_REL, __HIP_MEMORY_SCOPE_AGENT);
        while (__hip_atomic_load(&ctr[0], __ATOMIC_ACQUIRE, __HIP_MEMORY_SCOPE_AGENT) < GRID)
            __builtin_amdgcn_s_sleep(2);
    }
    __syncthreads();
    (void)__hip_atomic_load(&ctr[0], __ATOMIC_ACQUIRE, __HIP_MEMORY_SCOPE_AGENT);

    // ================= Phase CD =================
    float ipe[3];
#pragma unroll
    for (int r = 0; r < 3; ++r) {
        float pv = pel[r * 64 + l];
        float qq = pv * pv;
#pragma unroll
        for (int o = 1; o < 64; o <<= 1) qq += __shfl_xor(qq, o);
        ipe[r] = 1.f / fmaxf(sqrtf(qq), EPSV);
    }

    const float4* F = (const float4*)features;
    for (int grp = blockIdx.x; grp < BN / 4; grp += GRID) {
        int b0 = grp * 4;
        int b = b0 + w;
        cat_b[w * CSTRIDE + l] = features[(size_t)nodes[b] * FEATD + l];

#pragma unroll
        for (int r = 0; r < 3; ++r) {
            const int*   neigh = (r == 0) ? n1 : (r == 1) ? n2 : n3;
            const float* W     = (r == 0) ? W1 : (r == 1) ? W2 : W3;

            float s = -1e30f;
            int   n = 0;
            if (l < 32) {
                n = neigh[b * DEG + l];
                float4 sc = node_sc[n];
                float num = (r == 0) ? sc.x : (r == 1) ? sc.y : sc.z;
                s = num * ipe[r] / fmaxf(sc.w, EPSV);
            }
            int cnt = 0;
#pragma unroll
            for (int d2 = 0; d2 < 32; ++d2) {
                float v = __shfl(s, d2);
                cnt += ((v > s) || (v == s && d2 < l)) ? 1 : 0;
            }
            bool sel = (l < 32) && (cnt < k);
            if (sel) sel_ids[w][cnt] = n;

            float sp = sel ? s : 0.f;
            float sq = sel ? s * s : 0.f;
#pragma unroll
            for (int off = 32; off; off >>= 1) {
                sp += __shfl_down(sp, off);
                sq += __shfl_down(sq, off);
            }
            if (l == 0) {
                plossws[(r * 4096 + b) * 2]     = sp;
                plossws[(r * 4096 + b) * 2 + 1] = sq;
            }

            int col   = l & 15;
            int rbase = l >> 4;
            float4 a = make_float4(0.f, 0.f, 0.f, 0.f);
            if (k == 16) {
                int nid0 = sel_ids[w][rbase];
                int nid1 = sel_ids[w][rbase + 4];
                int nid2 = sel_ids[w][rbase + 8];
                int nid3 = sel_ids[w][rbase + 12];
                float4 v0 = F[(size_t)nid0 * 16 + col];
                float4 v1 = F[(size_t)nid1 * 16 + col];
                float4 v2 = F[(size_t)nid2 * 16 + col];
                float4 v3 = F[(size_t)nid3 * 16 + col];
                a.x = v0.x + v1.x + v2.x + v3.x;
                a.y = v0.y + v1.y + v2.y + v3.y;
                a.z = v0.z + v1.z + v2.z + v3.z;
                a.w = v0.w + v1.w + v2.w + v3.w;
            } else {
                for (int row0 = 0; row0 < k; row0 += 4) {
                    int row = row0 + rbase;
                    if (row < k) {
                        int nid = sel_ids[w][row];
                        float4 v = F[(size_t)nid * 16 + col];
                        a.x += v.x; a.y += v.y; a.z += v.z; a.w += v.w;
                    }
                }
            }
#pragma unroll
            for (int off = 16; off <= 32; off <<= 1) {
                a.x += __shfl_xor(a.x, off);
                a.y += __shfl_xor(a.y, off);
                a.z += __shfl_xor(a.z, off);
                a.w += __shfl_xor(a.w, off);
            }
            float inv_k = 1.f / (float)k;
            a.x *= inv_k; a.y *= inv_k; a.z *= inv_k; a.w *= inv_k;
            if (l < 16) aggl[w][l] = a;

            float acc = 0.f;
#pragma unroll
            for (int j4 = 0; j4 < 16; ++j4) {
                float4 ag = aggl[w][j4];
                acc += ag.x * W[(j4 * 4 + 0) * EMB + l]
                     + ag.y * W[(j4 * 4 + 1) * EMB + l]
                     + ag.z * W[(j4 * 4 + 2) * EMB + l]
                     + ag.w * W[(j4 * 4 + 3) * EMB + l];
            }
            cat_b[w * CSTRIDE + 64 + r * 64 + l] = fmaxf(acc, 0.f);
        }

        float acc0 = 0.f;
        const float* cp = &cat_b[w * CSTRIDE];
        for (int i0 = 0; i0 < 256; i0 += 16) {
            float wq[16];
#pragma unroll
            for (int u = 0; u < 16; ++u)
                wq[u] = weight[(i0 + u) * EMB + l];
#pragma unroll
            for (int u = 0; u < 16; ++u)
                acc0 += wq[u] * cp[i0 + u];
        }
        trans[w * 65 + l] = fmaxf(acc0, 0.f);
        __syncthreads();
        { int e = t >> 2, bb = t & 3;
          out[(size_t)e * BN + b0 + bb] = trans[bb * 65 + e]; }
        __syncthreads();
    }

    // ================= last-finisher loss tail =================
    __threadfence();
    if (t == 0) {
        int old = __hip_atomic_fetch_add(&ctr[1], 1, __ATOMIC_ACQ_REL, __HIP_MEMORY_SCOPE_AGENT);
        wflag = (old == GRID - 1);
    }
    __syncthreads();
    if (!wflag) return;
    (void)__hip_atomic_load(&ctr[1], __ATOMIC_ACQUIRE, __HIP_MEMORY_SCOPE_AGENT);

    float pv = (t < 192) ? pel[t] : 0.f;
    float q = pv * pv;
#pragma unroll
    for (int o = 1; o < 64; o <<= 1) q += __shfl_xor(q, o);
    if (t < 192 && l == 0)
        invpe_sm[w] = 1.f / fmaxf(sqrtf(q), EPSV);
    __syncthreads();

    float m0 = 0.f, m1 = 0.f, m2 = 0.f;
    for (int p = t; p < PP; p += 256) {
        int n = pos_nodes[p];
        float4 sc = node_sc[n];
        float invn = 1.f / fmaxf(sc.w, EPSV);
        m0 += sc.x * invpe_sm[0] * invn;
        m1 += sc.y * invpe_sm[1] * invn;
        m2 += sc.z * invpe_sm[2] * invn;
    }
#pragma unroll
    for (int o = 1; o < 64; o <<= 1) {
        m0 += __shfl_xor(m0, o);
        m1 += __shfl_xor(m1, o);
        m2 += __shfl_xor(m2, o);
    }
    if (l == 0) { wsum[w][0] = m0; wsum[w][1] = m1; wsum[w][2] = m2; }

    if (w < 3) {
        float s1 = 0.f, s2 = 0.f;
        const float2* pl2 = (const float2*)plossws;
        for (int i = l; i < 4096; i += 64) {
            float2 v = pl2[w * 4096 + i];
            s1 += v.x; s2 += v.y;
        }
#pragma unroll
        for (int o = 1; o < 64; o <<= 1) {
            s1 += __shfl_xor(s1, o);
            s2 += __shfl_xor(s2, o);
        }
        if (l == 0) { lsum[w][0] = s1; lsum[w][1] = s2; }
    }
    __syncthreads();

    if (t == 0) {
        float N = (float)BN * (float)k;
        float loss = 0.f;
#pragma unroll
        for (int r = 0; r < 3; ++r) {
            float mp = (wsum[0][r] + wsum[1][r] + wsum[2][r] + wsum[3][r])
                       / (float)PP;
            float s1 = lsum[r][0], s2 = lsum[r][1];
            loss += s2 / N - 2.f * mp * s1 / N + mp * mp;
        }
        out[(size_t)EMB * BN] = loss / 3.f;
    }
}

// ----------------------------------------------------------------
extern "C" void kernel_launch(void* const* d_in, const int* in_sizes, int n_in,
                              void* d_out, int out_size, void* d_ws, size_t ws_size,
                              hipStream_t stream) {
    const int*   nodes     = (const int*)  d_in[0];
    // d_in[1] labels: unused
    const int*   neigh1    = (const int*)  d_in[2];
    const int*   neigh2    = (const int*)  d_in[3];
    const int*   neigh3    = (const int*)  d_in[4];
    const int*   pos_nodes = (const int*)  d_in[5];
    const float* features  = (const float*)d_in[6];
    const float* weight    = (const float*)d_in[7];
    const float* rsim      = (const float*)d_in[8];
    const float* pos_embs  = (const float*)d_in[9];
    const float* W1        = (const float*)d_in[10];
    const float* W2        = (const float*)d_in[11];
    const float* W3        = (const float*)d_in[12];
    const int*   smp       = (const int*)  d_in[13];
    float* out = (float*)d_out;
    float* ws  = (float*)d_ws;

    float4* node_sc = (float4*)(ws + WS_SC);
    int*    ctr     = (int*)(ws + WS_CTR);
    float*  plossws = ws + WS_PL;

    hipMemsetAsync((void*)ctr, 0, 8, stream);    // barrier + finisher counters
    fused_all<<<dim3(GRID), dim3(256), 0, stream>>>(
        nodes, neigh1, neigh2, neigh3, pos_nodes, features, weight,
        rsim, pos_embs, W1, W2, W3, smp, node_sc, plossws, ctr, out);
}